// Round 12
// baseline (77.908 us; speedup 1.0000x reference)
//
#include <hip/hip_runtime.h>
#include <hip/hip_bf16.h>

// B=2, S=1024, E=512, H=2048, P=128, W=257
#define S_LEN 1024
#define E_DIM 512
#define H_DIM 2048
#define EXTA 1296              // 128 front pad + 1024 + 128 back pad + 16 zeros (band tiles)
#define BS_ROWS 2048

typedef __attribute__((ext_vector_type(8))) short bf16x8;
typedef __attribute__((ext_vector_type(4))) float f32x4;

__device__ inline ushort f2bf(float x) {
  union { float f; unsigned u; } c; c.f = x;
  unsigned u = c.u;
  u += 0x7fffu + ((u >> 16) & 1u);   // RNE
  return (ushort)(u >> 16);
}
__device__ inline float bf2f(ushort u) {
  union { unsigned u; float f; } c;
  c.u = ((unsigned)u) << 16;
  return c.f;
}

__device__ inline void gload16(ushort* dst, const ushort* src) {
  __builtin_amdgcn_global_load_lds(
      (const __attribute__((address_space(1))) void*)src,
      (__attribute__((address_space(3))) void*)dst, 16, 0, 0);
}

// ---------------- prep: PE add (pair-mapped, fast trig), wqkv transposes, pad fill ----------------
__global__ __launch_bounds__(256) void prep_kernel(const float* __restrict__ x,
                                                   const float* __restrict__ wq,
                                                   const float* __restrict__ wk,
                                                   const float* __restrict__ wv,
                                                   const float* __restrict__ bk,
                                                   const float* __restrict__ bv,
                                                   ushort* __restrict__ xpe_bf,
                                                   ushort* __restrict__ wqkvT,
                                                   ushort* __restrict__ k_bf,
                                                   ushort* __restrict__ v_t) {
  __shared__ float t[32][33];
  const int blk = blockIdx.x;
  if (blk < 1024) {
    int idx = blk * 256 + threadIdx.x;   // pair index: s in [0,1024), ep in [0,256)
    int ep = idx & 255;
    int s = idx >> 8;
    int e0 = ep * 2;
    const float c = -9.210340371976184f / 512.0f;  // -ln(10000)/E
    float freq = __expf((float)e0 * c);
    float sn, cs;
    __sincosf((float)s * freq, &sn, &cs);
    size_t base = (size_t)s * E_DIM + e0;
    float2 x0 = *(const float2*)(x + base);
    float2 x1 = *(const float2*)(x + base + S_LEN * E_DIM);
    ushort2 o0, o1;
    o0.x = f2bf(x0.x + sn); o0.y = f2bf(x0.y + cs);
    o1.x = f2bf(x1.x + sn); o1.y = f2bf(x1.y + cs);
    *(ushort2*)(xpe_bf + base) = o0;
    *(ushort2*)(xpe_bf + base + S_LEN * E_DIM) = o1;
  } else if (blk < 1792) {
    const int tile = blk - 1024;           // 0..767
    const int sect = tile >> 8, tt = tile & 255;
    const float* W = sect == 0 ? wq : (sect == 1 ? wk : wv);
    ushort* WT = wqkvT + (size_t)sect * 512 * 512;
    const int bx = tt & 15, by = tt >> 4;  // K=512, N=512
    int lx = threadIdx.x & 31, ly = threadIdx.x >> 5;  // 32 x 8
    int n0 = bx * 32, k0 = by * 32;
#pragma unroll
    for (int r = 0; r < 4; ++r)
      t[ly + r * 8][lx] = W[(size_t)(k0 + ly + r * 8) * 512 + n0 + lx];
    __syncthreads();
#pragma unroll
    for (int r = 0; r < 4; ++r)
      WT[(size_t)(n0 + ly + r * 8) * 512 + k0 + lx] = f2bf(t[lx][ly + r * 8]);
  } else {
    int p = (blk - 1792) * 256 + threadIdx.x;  // 2 tensors * 2 batch * 272 * 512
    int t2 = p / (2 * 272 * 512);
    int r2 = p % (2 * 272 * 512);
    int b = r2 / (272 * 512);
    int r3 = r2 % (272 * 512);
    if (t2 == 0) {
      int rr = r3 >> 9, e = r3 & 511;
      int row = rr < 128 ? rr : 1024 + rr;   // front 0..127, back 1152..1279, zeros 1280..1295
      float v = rr < 256 ? bk[e] : 0.f;
      k_bf[((size_t)b * EXTA + row) * 512 + e] = f2bf(v);
    } else {
      int n = r3 / 272, jj = r3 % 272;
      int j = jj < 128 ? jj : 1024 + jj;
      float v = jj < 256 ? bv[n] : 0.f;
      v_t[((size_t)b * 512 + n) * EXTA + j] = f2bf(v);
    }
  }
}

// ---------------- QKV GEMM (64x64 tiles, 768 blocks, 2-phase, XCD-chunked) ----------------
__global__ __launch_bounds__(256, 4) void qkv_kernel(const ushort* __restrict__ A,
                                                     const ushort* __restrict__ Bt,
                                                     const float* __restrict__ bq,
                                                     const float* __restrict__ bk,
                                                     const float* __restrict__ bv,
                                                     ushort* __restrict__ q_out,
                                                     ushort* __restrict__ k_out,
                                                     ushort* __restrict__ v_out) {
  __shared__ ushort As[2][64 * 64];
  __shared__ ushort Bs[2][64 * 64];
  // XCD-chunked swizzle: 768 = 8 x 96; XCD (bid&7) owns 96 contiguous tiles
  const int blk = (blockIdx.x & 7) * 96 + (blockIdx.x >> 3);
  const int tid = threadIdx.x;
  const int lane = tid & 63;
  const int w = tid >> 6;
  const int wr = w >> 1, wc = w & 1;   // 2x2 waves: WM=32, WN=32
  const int l15 = lane & 15, lhi = lane >> 4;
  const int col0 = (blk % 24) * 64, row0 = (blk / 24) * 64;

  int u0 = tid, u1 = 256 + tid;
  int ra0 = u0 >> 3, ca0 = ((u0 & 7) ^ (ra0 & 7)) * 8;
  int ra1 = u1 >> 3, ca1 = ((u1 & 7) ^ (ra1 & 7)) * 8;

  f32x4 acc[2][2] = {};

  gload16(&As[0][u0 * 8], &A[(size_t)(row0 + ra0) * 512 + ca0]);
  gload16(&As[0][u1 * 8], &A[(size_t)(row0 + ra1) * 512 + ca1]);
  gload16(&Bs[0][u0 * 8], &Bt[(size_t)(col0 + ra0) * 512 + ca0]);
  gload16(&Bs[0][u1 * 8], &Bt[(size_t)(col0 + ra1) * 512 + ca1]);

  for (int t = 0; t < 8; ++t) {
    const int cur = t & 1;
    if (t < 7) {
      int k0 = (t + 1) * 64;
      gload16(&As[cur ^ 1][u0 * 8], &A[(size_t)(row0 + ra0) * 512 + k0 + ca0]);
      gload16(&As[cur ^ 1][u1 * 8], &A[(size_t)(row0 + ra1) * 512 + k0 + ca1]);
      gload16(&Bs[cur ^ 1][u0 * 8], &Bt[(size_t)(col0 + ra0) * 512 + k0 + ca0]);
      gload16(&Bs[cur ^ 1][u1 * 8], &Bt[(size_t)(col0 + ra1) * 512 + k0 + ca1]);
      asm volatile("s_waitcnt vmcnt(4)" ::: "memory");
    } else {
      asm volatile("s_waitcnt vmcnt(0)" ::: "memory");
    }
    __builtin_amdgcn_s_barrier();
    __builtin_amdgcn_sched_barrier(0);
#pragma unroll
    for (int kk = 0; kk < 2; ++kk) {
      bf16x8 af[2], bfr[2];
#pragma unroll
      for (int mi = 0; mi < 2; ++mi) {
        int r = wr * 32 + mi * 16 + l15;
        int c16 = (kk * 4 + lhi) ^ (r & 7);
        af[mi] = *(const bf16x8*)&As[cur][r * 64 + c16 * 8];
      }
#pragma unroll
      for (int ni = 0; ni < 2; ++ni) {
        int r = wc * 32 + ni * 16 + l15;
        int c16 = (kk * 4 + lhi) ^ (r & 7);
        bfr[ni] = *(const bf16x8*)&Bs[cur][r * 64 + c16 * 8];
      }
#pragma unroll
      for (int mi = 0; mi < 2; ++mi)
#pragma unroll
        for (int ni = 0; ni < 2; ++ni)
          acc[mi][ni] = __builtin_amdgcn_mfma_f32_16x16x32_bf16(af[mi], bfr[ni], acc[mi][ni], 0, 0, 0);
    }
    __builtin_amdgcn_sched_barrier(0);
    __builtin_amdgcn_s_barrier();
  }

#pragma unroll
  for (int mi = 0; mi < 2; ++mi) {
    int mbase = row0 + wr * 32 + mi * 16 + lhi * 4;
#pragma unroll
    for (int ni = 0; ni < 2; ++ni) {
      int n = col0 + wc * 32 + ni * 16 + l15;
      int sect = n >> 9, nn = n & 511;
      float b = sect == 0 ? bq[nn] : (sect == 1 ? bk[nn] : bv[nn]);
      int bb = mbase >> 10;
      int s = mbase & 1023;
      if (sect == 0) {
#pragma unroll
        for (int j = 0; j < 4; ++j)
          q_out[(size_t)(mbase + j) * 512 + nn] = f2bf(acc[mi][ni][j] + b);
      } else if (sect == 1) {
#pragma unroll
        for (int j = 0; j < 4; ++j)
          k_out[((size_t)bb * EXTA + 128 + s + j) * 512 + nn] = f2bf(acc[mi][ni][j] + b);
      } else {
        ushort4 pk;
        pk.x = f2bf(acc[mi][ni][0] + b);
        pk.y = f2bf(acc[mi][ni][1] + b);
        pk.z = f2bf(acc[mi][ni][2] + b);
        pk.w = f2bf(acc[mi][ni][3] + b);
        *(ushort4*)&v_out[((size_t)bb * 512 + nn) * EXTA + 128 + s] = pk;
      }
    }
  }
}

// ---------------- generic 64x64 MFMA GEMM, 2-phase dbuf, XCD-chunked ----------------
// OUT 1 = bf16+bias+relu; 0 = fp32 (no bias). NTILES = grid/8 per XCD chunk, NCOL = tiles per row
template <int OUT, int CHUNK, int NCOL>
__global__ __launch_bounds__(256, 4) void mfma_gemm(const ushort* __restrict__ A,
                                                    const ushort* __restrict__ Bt,
                                                    const float* __restrict__ bias,
                                                    void* __restrict__ Cout,
                                                    int M, int N, int K, int LDA) {
  __shared__ ushort As[2][64 * 64];
  __shared__ ushort Bs[2][64 * 64];
  const int blk = (blockIdx.x & 7) * CHUNK + (blockIdx.x >> 3);
  const int tid = threadIdx.x;
  const int lane = tid & 63;
  const int w = tid >> 6;
  const int wr = w >> 1, wc = w & 1;   // 2x2 waves: WM=32, WN=32
  const int l15 = lane & 15, lhi = lane >> 4;
  const int col0 = (blk % NCOL) * 64, row0 = (blk / NCOL) * 64;
  const int nt = K >> 6;

  int u0 = tid, u1 = 256 + tid;
  int ra0 = u0 >> 3, ca0 = ((u0 & 7) ^ (ra0 & 7)) * 8;
  int ra1 = u1 >> 3, ca1 = ((u1 & 7) ^ (ra1 & 7)) * 8;
  const ushort* Abase = A + (size_t)row0 * LDA;
  const ushort* Bbase = Bt + (size_t)col0 * LDA;

  f32x4 acc[2][2] = {};

  gload16(&As[0][u0 * 8], &Abase[(size_t)ra0 * LDA + ca0]);
  gload16(&As[0][u1 * 8], &Abase[(size_t)ra1 * LDA + ca1]);
  gload16(&Bs[0][u0 * 8], &Bbase[(size_t)ra0 * LDA + ca0]);
  gload16(&Bs[0][u1 * 8], &Bbase[(size_t)ra1 * LDA + ca1]);

  for (int t = 0; t < nt; ++t) {
    const int cur = t & 1;
    if (t + 1 < nt) {
      int k0 = (t + 1) * 64;
      gload16(&As[cur ^ 1][u0 * 8], &Abase[(size_t)ra0 * LDA + k0 + ca0]);
      gload16(&As[cur ^ 1][u1 * 8], &Abase[(size_t)ra1 * LDA + k0 + ca1]);
      gload16(&Bs[cur ^ 1][u0 * 8], &Bbase[(size_t)ra0 * LDA + k0 + ca0]);
      gload16(&Bs[cur ^ 1][u1 * 8], &Bbase[(size_t)ra1 * LDA + k0 + ca1]);
      asm volatile("s_waitcnt vmcnt(4)" ::: "memory");
    } else {
      asm volatile("s_waitcnt vmcnt(0)" ::: "memory");
    }
    __builtin_amdgcn_s_barrier();
    __builtin_amdgcn_sched_barrier(0);
#pragma unroll
    for (int kk = 0; kk < 2; ++kk) {
      bf16x8 af[2], bfr[2];
#pragma unroll
      for (int mi = 0; mi < 2; ++mi) {
        int r = wr * 32 + mi * 16 + l15;
        int c16 = (kk * 4 + lhi) ^ (r & 7);
        af[mi] = *(const bf16x8*)&As[cur][r * 64 + c16 * 8];
      }
#pragma unroll
      for (int ni = 0; ni < 2; ++ni) {
        int r = wc * 32 + ni * 16 + l15;
        int c16 = (kk * 4 + lhi) ^ (r & 7);
        bfr[ni] = *(const bf16x8*)&Bs[cur][r * 64 + c16 * 8];
      }
#pragma unroll
      for (int mi = 0; mi < 2; ++mi)
#pragma unroll
        for (int ni = 0; ni < 2; ++ni)
          acc[mi][ni] = __builtin_amdgcn_mfma_f32_16x16x32_bf16(af[mi], bfr[ni], acc[mi][ni], 0, 0, 0);
    }
    __builtin_amdgcn_sched_barrier(0);
    __builtin_amdgcn_s_barrier();
  }

#pragma unroll
  for (int mi = 0; mi < 2; ++mi) {
    int mbase = row0 + wr * 32 + mi * 16 + lhi * 4;
#pragma unroll
    for (int ni = 0; ni < 2; ++ni) {
      int n = col0 + wc * 32 + ni * 16 + l15;
      if constexpr (OUT == 1) {
        float b = bias[n];
        ushort* C = (ushort*)Cout;
#pragma unroll
        for (int j = 0; j < 4; ++j)
          C[(size_t)(mbase + j) * N + n] = f2bf(fmaxf(acc[mi][ni][j] + b, 0.f));
      } else {
        float* C = (float*)Cout;
#pragma unroll
        for (int j = 0; j < 4; ++j) C[(size_t)(mbase + j) * N + n] = acc[mi][ni][j];
      }
    }
  }
}

// ---------------- attention + LN1 (16 waves, 128 tiles XCD-chunked) + w1/w2 transposes ----------------
union AttnSm {
  struct {
    float e[16][292];
    ushort p[16][296];
    float inv[16];
    float redS[16][16];
    float redQ[16][16];
    float mu[16], rs[16];
  } a;
  float t[32][33];
};

__global__ __launch_bounds__(1024) void attn_ln1(const ushort* __restrict__ qb,
                                                 const ushort* __restrict__ kb,
                                                 const ushort* __restrict__ vt,
                                                 const ushort* __restrict__ xpe_bf,
                                                 const float* __restrict__ ln1w,
                                                 const float* __restrict__ ln1b,
                                                 const float* __restrict__ w1,
                                                 const float* __restrict__ w2,
                                                 ushort* __restrict__ w1T,
                                                 ushort* __restrict__ w2T,
                                                 ushort* __restrict__ x1bf) {
  __shared__ AttnSm sm;
  const int tid = threadIdx.x;

  if (blockIdx.x >= 128) {  // weight transposes, 1024 threads: 32 lx x 32 ly
    const int tile = blockIdx.x - 128;   // 0..2047
    const float* W; ushort* WT; int K, N, bx, by;
    if (tile < 1024) {
      K = 512; N = 2048; W = w1; WT = w1T;
      bx = tile & 63; by = tile >> 6;
    } else {
      K = 2048; N = 512; W = w2; WT = w2T;
      int tt = tile - 1024; bx = tt & 15; by = tt >> 4;
    }
    int lx = tid & 31, ly = tid >> 5;  // ly 0..31
    int n0 = bx * 32, k0 = by * 32;
    sm.t[ly][lx] = W[(size_t)(k0 + ly) * N + n0 + lx];
    __syncthreads();
    WT[(size_t)(n0 + ly) * K + k0 + lx] = f2bf(sm.t[lx][ly]);
    return;
  }

  const int lane = tid & 63;
  const int w = tid >> 6;          // 0..15
  const int l15 = lane & 15, lhi = lane >> 4;
  // XCD-chunked: XCD (bid&7) owns 16 contiguous s-tiles -> K/V window ~1MB, L2-resident
  const int tile = (blockIdx.x & 7) * 16 + (blockIdx.x >> 3);  // 0..127
  const int b = tile >> 6;
  const int s0 = (tile & 63) * 16;
  const int base0 = b * 1024 + s0;

  const ushort* qrow = qb + (size_t)(base0 + l15) * 512 + lhi * 8;
  bf16x8 qf[16];
#pragma unroll
  for (int ks = 0; ks < 16; ++ks) qf[ks] = *(const bf16x8*)(qrow + ks * 32);

  const float scale = 0.044194173824159216f;  // 1/sqrt(512)
  const ushort* kbase = kb + (size_t)b * EXTA * 512 + (size_t)(s0 + l15) * 512 + lhi * 8;

  // energy: wave w -> j-tiles {w, w+16}
  for (int jt = w; jt < 18; jt += 16) {
    f32x4 acc = {};
    const ushort* kp = kbase + (size_t)jt * 16 * 512;
#pragma unroll
    for (int ks = 0; ks < 16; ++ks) {
      bf16x8 kf = *(const bf16x8*)(kp + ks * 32);
      acc = __builtin_amdgcn_mfma_f32_16x16x32_bf16(qf[ks], kf, acc, 0, 0, 0);
    }
    int jc = jt * 16 + l15;
#pragma unroll
    for (int j = 0; j < 4; ++j) {
      int i = lhi * 4 + j;
      bool valid = (jc >= i) && (jc <= i + 256);
      sm.a.e[i][jc] = valid ? acc[j] * scale : -1e30f;
    }
  }
  __syncthreads();

  // softmax: one wave per row, 64 lanes over 288 cols (t=4 valid iff lane<32)
  {
    int r = w;
    float m = -1e30f;
#pragma unroll
    for (int t = 0; t < 5; ++t) {
      int col = lane + 64 * t;
      float e = (t < 4 || lane < 32) ? sm.a.e[r][col] : -1e30f;
      m = fmaxf(m, e);
    }
#pragma unroll
    for (int off = 1; off <= 32; off <<= 1) m = fmaxf(m, __shfl_xor(m, off));
    float s = 0.f;
#pragma unroll
    for (int t = 0; t < 5; ++t) {
      int col = lane + 64 * t;
      if (t < 4 || lane < 32) {
        float p = __expf(sm.a.e[r][col] - m);
        s += p;
        sm.a.p[r][col] = f2bf(p);
      }
    }
#pragma unroll
    for (int off = 1; off <= 32; off <<= 1) s += __shfl_xor(s, off);
    if (lane == 0) sm.a.inv[r] = 1.0f / s;
  }
  __syncthreads();

  // PV: wave w -> n-tiles {2w, 2w+1}; bf16 residual
  bf16x8 pf[9];
#pragma unroll
  for (int ks = 0; ks < 9; ++ks) pf[ks] = *(const bf16x8*)&sm.a.p[l15][ks * 32 + lhi * 8];
  float inv[4];
#pragma unroll
  for (int j = 0; j < 4; ++j) inv[j] = sm.a.inv[lhi * 4 + j];

  const ushort* vbase = vt + (size_t)b * 512 * EXTA + s0 + lhi * 8;
  float val[2][4];  // [ni][j]
#pragma unroll
  for (int ni = 0; ni < 2; ++ni) {
    int n = w * 32 + ni * 16 + l15;
    f32x4 acc = {};
    const ushort* vp = vbase + (size_t)n * EXTA;
#pragma unroll
    for (int ks = 0; ks < 9; ++ks) {
      bf16x8 vf = *(const bf16x8*)(vp + ks * 32);
      acc = __builtin_amdgcn_mfma_f32_16x16x32_bf16(pf[ks], vf, acc, 0, 0, 0);
    }
#pragma unroll
    for (int j = 0; j < 4; ++j) {
      int r = lhi * 4 + j;
      val[ni][j] = acc[j] * inv[j] + bf2f(xpe_bf[(size_t)(base0 + r) * 512 + n]);
    }
  }

  // LN1 stats
  float S[4], Q[4];
#pragma unroll
  for (int j = 0; j < 4; ++j) {
    S[j] = 0.f; Q[j] = 0.f;
#pragma unroll
    for (int ni = 0; ni < 2; ++ni) { S[j] += val[ni][j]; Q[j] += val[ni][j] * val[ni][j]; }
  }
#pragma unroll
  for (int off = 1; off <= 8; off <<= 1) {
#pragma unroll
    for (int j = 0; j < 4; ++j) {
      S[j] += __shfl_xor(S[j], off);
      Q[j] += __shfl_xor(Q[j], off);
    }
  }
  if (l15 == 0) {
#pragma unroll
    for (int j = 0; j < 4; ++j) { sm.a.redS[w][lhi * 4 + j] = S[j]; sm.a.redQ[w][lhi * 4 + j] = Q[j]; }
  }
  __syncthreads();
  if (tid < 16) {
    float sS = 0.f, sQ = 0.f;
#pragma unroll
    for (int ww = 0; ww < 16; ++ww) { sS += sm.a.redS[ww][tid]; sQ += sm.a.redQ[ww][tid]; }
    float mu = sS * (1.0f / 512.0f);
    float var = sQ * (1.0f / 512.0f) - mu * mu;
    sm.a.mu[tid] = mu;
    sm.a.rs[tid] = rsqrtf(var + 1e-5f);
  }
  __syncthreads();

#pragma unroll
  for (int ni = 0; ni < 2; ++ni) {
    int n = w * 32 + ni * 16 + l15;
    float lw = ln1w[n], lb = ln1b[n];
#pragma unroll
    for (int j = 0; j < 4; ++j) {
      int r = lhi * 4 + j;
      float o = (val[ni][j] - sm.a.mu[r]) * sm.a.rs[r] * lw + lb;
      x1bf[(size_t)(base0 + r) * 512 + n] = f2bf(o);
    }
  }
}

// ---------------- LN2: ff2 + bias + bf16 residual, layernorm ----------------
__device__ inline float wave_reduce_sum(float v) {
#pragma unroll
  for (int off = 32; off >= 1; off >>= 1) v += __shfl_xor(v, off);
  return v;
}

__global__ __launch_bounds__(256) void ln2_kernel(const float* __restrict__ ff2,
                                                  const float* __restrict__ ab,
                                                  const ushort* __restrict__ rsd_bf,
                                                  const float* __restrict__ w,
                                                  const float* __restrict__ bias,
                                                  float* __restrict__ out) {
  const int row = blockIdx.x;
  const int tid = threadIdx.x;
  __shared__ float red[8];
  const int e0 = tid * 2;
  const size_t base = (size_t)row * E_DIM + e0;
  float2 v0 = *(const float2*)(ff2 + base);
  float2 bb = *(const float2*)(ab + e0);
  ushort2 rv = *(const ushort2*)(rsd_bf + base);
  float x0 = v0.x + bb.x + bf2f(rv.x);
  float x1 = v0.y + bb.y + bf2f(rv.y);

  float sm = wave_reduce_sum(x0 + x1);
  if ((tid & 63) == 0) red[tid >> 6] = sm;
  __syncthreads();
  float mu = (red[0] + red[1] + red[2] + red[3]) * (1.0f / 512.0f);
  float d0 = x0 - mu, d1 = x1 - mu;
  float vs = wave_reduce_sum(d0 * d0 + d1 * d1);
  if ((tid & 63) == 0) red[4 + (tid >> 6)] = vs;
  __syncthreads();
  float var = (red[4] + red[5] + red[6] + red[7]) * (1.0f / 512.0f);
  float inv = rsqrtf(var + 1e-5f);
  float2 wv = *(const float2*)(w + e0);
  float2 bi = *(const float2*)(bias + e0);
  float o0 = d0 * inv * wv.x + bi.x;
  float o1 = d1 * inv * wv.y + bi.y;
  *(float2*)(out + base) = make_float2(o0, o1);
}

// ---------------- launch ----------------
extern "C" void kernel_launch(void* const* d_in, const int* in_sizes, int n_in,
                              void* d_out, int out_size, void* d_ws, size_t ws_size,
                              hipStream_t stream) {
  const float* x    = (const float*)d_in[0];
  const float* wq   = (const float*)d_in[1];
  const float* bq   = (const float*)d_in[2];
  const float* wk   = (const float*)d_in[3];
  const float* bk   = (const float*)d_in[4];
  const float* wv   = (const float*)d_in[5];
  const float* bv   = (const float*)d_in[6];
  const float* w1   = (const float*)d_in[7];
  const float* b1   = (const float*)d_in[8];
  const float* w2   = (const float*)d_in[9];
  const float* b2   = (const float*)d_in[10];
  const float* ln1w = (const float*)d_in[11];
  const float* ln1b = (const float*)d_in[12];
  const float* ln2w = (const float*)d_in[13];
  const float* ln2b = (const float*)d_in[14];

  char* W = (char*)d_ws;
  ushort* xpebf  = (ushort*)(W);                     // 2MB  @0
  ushort* wqkvT  = (ushort*)(W + (2u  << 20));       // 1.5MB@2
  ushort* w1T    = (ushort*)(W + (4u  << 20));       // 2MB  @4
  ushort* w2T    = (ushort*)(W + (6u  << 20));       // 2MB  @6
  ushort* q_bf   = (ushort*)(W + (8u  << 20));       // 2MB  @8
  ushort* k_bf   = (ushort*)(W + (10u << 20));       // 2.6MB@10
  ushort* v_t    = (ushort*)(W + (13u << 20));       // 2.6MB@13
  ushort* x1bf   = (ushort*)(W + (16u << 20));       // 2MB  @16
  ushort* ff1_bf = (ushort*)(W + (18u << 20));       // 8MB  @18
  float*  ff2    = (float*)(W + (26u << 20));        // 4MB  @26

  // prep: PE + wqkv transposes + pads
  prep_kernel<<<3968, 256, 0, stream>>>(x, wq, wk, wv, bk, bv,
                                        xpebf, wqkvT, k_bf, v_t);

  // QKV fused (768 GEMM blocks, 64x64, 2-phase, XCD-chunked)
  qkv_kernel<<<768, 256, 0, stream>>>(xpebf, wqkvT, bq, bk, bv, q_bf, k_bf, v_t);

  // attention + LN1 (128 blocks XCD-chunked) + w1/w2 transposes (2048 blocks)
  attn_ln1<<<2176, 1024, 0, stream>>>(q_bf, k_bf, v_t, xpebf, ln1w, ln1b,
                                      w1, w2, w1T, w2T, x1bf);

  // FFN1: M=2048, N=2048, K=512, relu, bf16 out (1024 blocks, chunk=128, 32 cols)
  mfma_gemm<1, 128, 32><<<1024, 256, 0, stream>>>(
      x1bf, w1T, b1, ff1_bf, BS_ROWS, H_DIM, 512, 512);

  // FFN2: M=2048, N=512, K=2048 single-K fp32 out (256 blocks, chunk=32, 8 cols)
  mfma_gemm<0, 32, 8><<<256, 256, 0, stream>>>(
      ff1_bf, w2T, nullptr, ff2, BS_ROWS, E_DIM, 2048, 2048);

  // LN2: (ff2 + b2) + x1bf residual
  ln2_kernel<<<BS_ROWS, 256, 0, stream>>>(ff2, b2, x1bf, ln2w, ln2b, (float*)d_out);
}

// Round 13
// 70.483 us; speedup vs baseline: 1.1053x; 1.1053x over previous
//
#include <hip/hip_runtime.h>
#include <hip/hip_bf16.h>

// B=2, S=1024, E=512, H=2048, P=128, W=257
#define S_LEN 1024
#define E_DIM 512
#define H_DIM 2048
#define EXTA 1296              // 128 front pad + 1024 + 128 back pad + 16 zeros (band tiles)
#define BS_ROWS 2048

typedef __attribute__((ext_vector_type(8))) short bf16x8;
typedef __attribute__((ext_vector_type(4))) float f32x4;

__device__ inline ushort f2bf(float x) {
  union { float f; unsigned u; } c; c.f = x;
  unsigned u = c.u;
  u += 0x7fffu + ((u >> 16) & 1u);   // RNE
  return (ushort)(u >> 16);
}
__device__ inline float bf2f(ushort u) {
  union { unsigned u; float f; } c;
  c.u = ((unsigned)u) << 16;
  return c.f;
}

__device__ inline void gload16(ushort* dst, const ushort* src) {
  __builtin_amdgcn_global_load_lds(
      (const __attribute__((address_space(1))) void*)src,
      (__attribute__((address_space(3))) void*)dst, 16, 0, 0);
}

// ---------------- prep: PE add (pair-mapped, fast trig), wqkv transposes, pad fill ----------------
__global__ __launch_bounds__(256) void prep_kernel(const float* __restrict__ x,
                                                   const float* __restrict__ wq,
                                                   const float* __restrict__ wk,
                                                   const float* __restrict__ wv,
                                                   const float* __restrict__ bk,
                                                   const float* __restrict__ bv,
                                                   ushort* __restrict__ xpe_bf,
                                                   ushort* __restrict__ wqkvT,
                                                   ushort* __restrict__ k_bf,
                                                   ushort* __restrict__ v_t) {
  __shared__ float t[32][33];
  const int blk = blockIdx.x;
  if (blk < 1024) {
    int idx = blk * 256 + threadIdx.x;   // pair index: s in [0,1024), ep in [0,256)
    int ep = idx & 255;
    int s = idx >> 8;
    int e0 = ep * 2;
    const float c = -9.210340371976184f / 512.0f;  // -ln(10000)/E
    float freq = __expf((float)e0 * c);
    float sn, cs;
    __sincosf((float)s * freq, &sn, &cs);
    size_t base = (size_t)s * E_DIM + e0;
    float2 x0 = *(const float2*)(x + base);
    float2 x1 = *(const float2*)(x + base + S_LEN * E_DIM);
    ushort2 o0, o1;
    o0.x = f2bf(x0.x + sn); o0.y = f2bf(x0.y + cs);
    o1.x = f2bf(x1.x + sn); o1.y = f2bf(x1.y + cs);
    *(ushort2*)(xpe_bf + base) = o0;
    *(ushort2*)(xpe_bf + base + S_LEN * E_DIM) = o1;
  } else if (blk < 1792) {
    const int tile = blk - 1024;           // 0..767
    const int sect = tile >> 8, tt = tile & 255;
    const float* W = sect == 0 ? wq : (sect == 1 ? wk : wv);
    ushort* WT = wqkvT + (size_t)sect * 512 * 512;
    const int bx = tt & 15, by = tt >> 4;  // K=512, N=512
    int lx = threadIdx.x & 31, ly = threadIdx.x >> 5;  // 32 x 8
    int n0 = bx * 32, k0 = by * 32;
#pragma unroll
    for (int r = 0; r < 4; ++r)
      t[ly + r * 8][lx] = W[(size_t)(k0 + ly + r * 8) * 512 + n0 + lx];
    __syncthreads();
#pragma unroll
    for (int r = 0; r < 4; ++r)
      WT[(size_t)(n0 + ly + r * 8) * 512 + k0 + lx] = f2bf(t[lx][ly + r * 8]);
  } else {
    int p = (blk - 1792) * 256 + threadIdx.x;  // 2 tensors * 2 batch * 272 * 512
    int t2 = p / (2 * 272 * 512);
    int r2 = p % (2 * 272 * 512);
    int b = r2 / (272 * 512);
    int r3 = r2 % (272 * 512);
    if (t2 == 0) {
      int rr = r3 >> 9, e = r3 & 511;
      int row = rr < 128 ? rr : 1024 + rr;   // front 0..127, back 1152..1279, zeros 1280..1295
      float v = rr < 256 ? bk[e] : 0.f;
      k_bf[((size_t)b * EXTA + row) * 512 + e] = f2bf(v);
    } else {
      int n = r3 / 272, jj = r3 % 272;
      int j = jj < 128 ? jj : 1024 + jj;
      float v = jj < 256 ? bv[n] : 0.f;
      v_t[((size_t)b * 512 + n) * EXTA + j] = f2bf(v);
    }
  }
}

// ---------------- QKV GEMM (64x64 tiles, 768 blocks, 4 blocks/CU target) ----------------
__global__ __launch_bounds__(256, 4) void qkv_kernel(const ushort* __restrict__ A,
                                                     const ushort* __restrict__ Bt,
                                                     const float* __restrict__ bq,
                                                     const float* __restrict__ bk,
                                                     const float* __restrict__ bv,
                                                     ushort* __restrict__ q_out,
                                                     ushort* __restrict__ k_out,
                                                     ushort* __restrict__ v_out) {
  __shared__ ushort As[64 * 64];
  __shared__ ushort Bs[64 * 64];
  const int blk = blockIdx.x;
  const int tid = threadIdx.x;
  const int lane = tid & 63;
  const int w = tid >> 6;
  const int wr = w >> 1, wc = w & 1;   // 2x2 waves: WM=32, WN=32
  const int l15 = lane & 15, lhi = lane >> 4;
  const int col0 = (blk % 24) * 64, row0 = (blk / 24) * 64;

  f32x4 acc[2][2] = {};

  for (int k0 = 0; k0 < 512; k0 += 64) {
#pragma unroll
    for (int it = 0; it < 2; ++it) {
      int u = it * 256 + tid;
      int r = u >> 3;
      int c16 = (u & 7) ^ (r & 7);
      gload16(&As[(size_t)u * 8], &A[(size_t)(row0 + r) * 512 + k0 + c16 * 8]);
    }
#pragma unroll
    for (int it = 0; it < 2; ++it) {
      int u = it * 256 + tid;
      int r = u >> 3;
      int c16 = (u & 7) ^ (r & 7);
      gload16(&Bs[(size_t)u * 8], &Bt[(size_t)(col0 + r) * 512 + k0 + c16 * 8]);
    }
    __syncthreads();
#pragma unroll
    for (int kk = 0; kk < 2; ++kk) {
      bf16x8 af[2], bfr[2];
#pragma unroll
      for (int mi = 0; mi < 2; ++mi) {
        int r = wr * 32 + mi * 16 + l15;
        int c16 = (kk * 4 + lhi) ^ (r & 7);
        af[mi] = *(const bf16x8*)&As[r * 64 + c16 * 8];
      }
#pragma unroll
      for (int ni = 0; ni < 2; ++ni) {
        int r = wc * 32 + ni * 16 + l15;
        int c16 = (kk * 4 + lhi) ^ (r & 7);
        bfr[ni] = *(const bf16x8*)&Bs[r * 64 + c16 * 8];
      }
#pragma unroll
      for (int mi = 0; mi < 2; ++mi)
#pragma unroll
        for (int ni = 0; ni < 2; ++ni)
          acc[mi][ni] = __builtin_amdgcn_mfma_f32_16x16x32_bf16(af[mi], bfr[ni], acc[mi][ni], 0, 0, 0);
    }
    __syncthreads();
  }

#pragma unroll
  for (int mi = 0; mi < 2; ++mi) {
    int mbase = row0 + wr * 32 + mi * 16 + lhi * 4;
#pragma unroll
    for (int ni = 0; ni < 2; ++ni) {
      int n = col0 + wc * 32 + ni * 16 + l15;
      int sect = n >> 9, nn = n & 511;
      float b = sect == 0 ? bq[nn] : (sect == 1 ? bk[nn] : bv[nn]);
      int bb = mbase >> 10;
      int s = mbase & 1023;
      if (sect == 0) {
#pragma unroll
        for (int j = 0; j < 4; ++j)
          q_out[(size_t)(mbase + j) * 512 + nn] = f2bf(acc[mi][ni][j] + b);
      } else if (sect == 1) {
#pragma unroll
        for (int j = 0; j < 4; ++j)
          k_out[((size_t)bb * EXTA + 128 + s + j) * 512 + nn] = f2bf(acc[mi][ni][j] + b);
      } else {
        ushort4 pk;
        pk.x = f2bf(acc[mi][ni][0] + b);
        pk.y = f2bf(acc[mi][ni][1] + b);
        pk.z = f2bf(acc[mi][ni][2] + b);
        pk.w = f2bf(acc[mi][ni][3] + b);
        *(ushort4*)&v_out[((size_t)bb * 512 + nn) * EXTA + 128 + s] = pk;
      }
    }
  }
}

// ---------------- generic 64x64 MFMA GEMM: OUT 1 = bf16+bias+relu; 3 = fp32 split-K partial ----------------
template <int OUT>
__global__ __launch_bounds__(256, 4) void mfma_gemm(const ushort* __restrict__ A,
                                                    const ushort* __restrict__ Bt,
                                                    const float* __restrict__ bias,
                                                    void* __restrict__ Cout,
                                                    int M, int N, int K, int LDA) {
  __shared__ ushort As[64 * 64];
  __shared__ ushort Bs[64 * 64];
  const int tid = threadIdx.x;
  const int lane = tid & 63;
  const int w = tid >> 6;
  const int wr = w >> 1, wc = w & 1;   // 2x2 waves: WM=32, WN=32
  const int l15 = lane & 15, lhi = lane >> 4;
  const int col0 = blockIdx.x * 64, row0 = blockIdx.y * 64;
  const int koff = blockIdx.z * K;

  f32x4 acc[2][2] = {};

  for (int k0 = 0; k0 < K; k0 += 64) {
#pragma unroll
    for (int it = 0; it < 2; ++it) {
      int u = it * 256 + tid;
      int r = u >> 3;
      int c16 = (u & 7) ^ (r & 7);
      gload16(&As[(size_t)u * 8], &A[(size_t)(row0 + r) * LDA + koff + k0 + c16 * 8]);
    }
#pragma unroll
    for (int it = 0; it < 2; ++it) {
      int u = it * 256 + tid;
      int r = u >> 3;
      int c16 = (u & 7) ^ (r & 7);
      gload16(&Bs[(size_t)u * 8], &Bt[(size_t)(col0 + r) * LDA + koff + k0 + c16 * 8]);
    }
    __syncthreads();
#pragma unroll
    for (int kk = 0; kk < 2; ++kk) {
      bf16x8 af[2], bfr[2];
#pragma unroll
      for (int mi = 0; mi < 2; ++mi) {
        int r = wr * 32 + mi * 16 + l15;
        int c16 = (kk * 4 + lhi) ^ (r & 7);
        af[mi] = *(const bf16x8*)&As[r * 64 + c16 * 8];
      }
#pragma unroll
      for (int ni = 0; ni < 2; ++ni) {
        int r = wc * 32 + ni * 16 + l15;
        int c16 = (kk * 4 + lhi) ^ (r & 7);
        bfr[ni] = *(const bf16x8*)&Bs[r * 64 + c16 * 8];
      }
#pragma unroll
      for (int mi = 0; mi < 2; ++mi)
#pragma unroll
        for (int ni = 0; ni < 2; ++ni)
          acc[mi][ni] = __builtin_amdgcn_mfma_f32_16x16x32_bf16(af[mi], bfr[ni], acc[mi][ni], 0, 0, 0);
    }
    __syncthreads();
  }

#pragma unroll
  for (int mi = 0; mi < 2; ++mi) {
    int mbase = row0 + wr * 32 + mi * 16 + lhi * 4;
#pragma unroll
    for (int ni = 0; ni < 2; ++ni) {
      int n = col0 + wc * 32 + ni * 16 + l15;
      if constexpr (OUT == 1) {
        float b = bias[n];
        ushort* C = (ushort*)Cout;
#pragma unroll
        for (int j = 0; j < 4; ++j)
          C[(size_t)(mbase + j) * N + n] = f2bf(fmaxf(acc[mi][ni][j] + b, 0.f));
      } else {
        float* C = (float*)Cout + (size_t)blockIdx.z * M * N;
#pragma unroll
        for (int j = 0; j < 4; ++j) C[(size_t)(mbase + j) * N + n] = acc[mi][ni][j];
      }
    }
  }
}

// ---------------- attention + LN1 (16 waves, blocks 0..127) + w1/w2 transposes ----------------
union AttnSm {
  struct {
    float e[16][292];
    ushort p[16][296];
    float inv[16];
    float redS[16][16];
    float redQ[16][16];
    float mu[16], rs[16];
  } a;
  float t[32][33];
};

__global__ __launch_bounds__(1024) void attn_ln1(const ushort* __restrict__ qb,
                                                 const ushort* __restrict__ kb,
                                                 const ushort* __restrict__ vt,
                                                 const ushort* __restrict__ xpe_bf,
                                                 const float* __restrict__ ln1w,
                                                 const float* __restrict__ ln1b,
                                                 const float* __restrict__ w1,
                                                 const float* __restrict__ w2,
                                                 ushort* __restrict__ w1T,
                                                 ushort* __restrict__ w2T,
                                                 ushort* __restrict__ x1bf) {
  __shared__ AttnSm sm;
  const int tid = threadIdx.x;

  if (blockIdx.x >= 128) {  // weight transposes, 1024 threads: 32 lx x 32 ly
    const int tile = blockIdx.x - 128;   // 0..2047
    const float* W; ushort* WT; int K, N, bx, by;
    if (tile < 1024) {
      K = 512; N = 2048; W = w1; WT = w1T;
      bx = tile & 63; by = tile >> 6;
    } else {
      K = 2048; N = 512; W = w2; WT = w2T;
      int tt = tile - 1024; bx = tt & 15; by = tt >> 4;
    }
    int lx = tid & 31, ly = tid >> 5;  // ly 0..31
    int n0 = bx * 32, k0 = by * 32;
    sm.t[ly][lx] = W[(size_t)(k0 + ly) * N + n0 + lx];
    __syncthreads();
    WT[(size_t)(n0 + ly) * K + k0 + lx] = f2bf(sm.t[lx][ly]);
    return;
  }

  const int lane = tid & 63;
  const int w = tid >> 6;          // 0..15
  const int l15 = lane & 15, lhi = lane >> 4;
  const int tile = blockIdx.x;     // 0..127
  const int b = tile >> 6;
  const int s0 = (tile & 63) * 16;
  const int base0 = b * 1024 + s0;

  const ushort* qrow = qb + (size_t)(base0 + l15) * 512 + lhi * 8;
  bf16x8 qf[16];
#pragma unroll
  for (int ks = 0; ks < 16; ++ks) qf[ks] = *(const bf16x8*)(qrow + ks * 32);

  const float scale = 0.044194173824159216f;  // 1/sqrt(512)
  const ushort* kbase = kb + (size_t)b * EXTA * 512 + (size_t)(s0 + l15) * 512 + lhi * 8;

  // energy: wave w -> j-tiles {w, w+16}
  for (int jt = w; jt < 18; jt += 16) {
    f32x4 acc = {};
    const ushort* kp = kbase + (size_t)jt * 16 * 512;
#pragma unroll
    for (int ks = 0; ks < 16; ++ks) {
      bf16x8 kf = *(const bf16x8*)(kp + ks * 32);
      acc = __builtin_amdgcn_mfma_f32_16x16x32_bf16(qf[ks], kf, acc, 0, 0, 0);
    }
    int jc = jt * 16 + l15;
#pragma unroll
    for (int j = 0; j < 4; ++j) {
      int i = lhi * 4 + j;
      bool valid = (jc >= i) && (jc <= i + 256);
      sm.a.e[i][jc] = valid ? acc[j] * scale : -1e30f;
    }
  }
  __syncthreads();

  // softmax: one wave per row, 64 lanes over 288 cols (t=4 valid iff lane<32)
  {
    int r = w;
    float m = -1e30f;
#pragma unroll
    for (int t = 0; t < 5; ++t) {
      int col = lane + 64 * t;
      float e = (t < 4 || lane < 32) ? sm.a.e[r][col] : -1e30f;
      m = fmaxf(m, e);
    }
#pragma unroll
    for (int off = 1; off <= 32; off <<= 1) m = fmaxf(m, __shfl_xor(m, off));
    float s = 0.f;
#pragma unroll
    for (int t = 0; t < 5; ++t) {
      int col = lane + 64 * t;
      if (t < 4 || lane < 32) {
        float p = __expf(sm.a.e[r][col] - m);
        s += p;
        sm.a.p[r][col] = f2bf(p);
      }
    }
#pragma unroll
    for (int off = 1; off <= 32; off <<= 1) s += __shfl_xor(s, off);
    if (lane == 0) sm.a.inv[r] = 1.0f / s;
  }
  __syncthreads();

  // PV: wave w -> n-tiles {2w, 2w+1}; bf16 residual
  bf16x8 pf[9];
#pragma unroll
  for (int ks = 0; ks < 9; ++ks) pf[ks] = *(const bf16x8*)&sm.a.p[l15][ks * 32 + lhi * 8];
  float inv[4];
#pragma unroll
  for (int j = 0; j < 4; ++j) inv[j] = sm.a.inv[lhi * 4 + j];

  const ushort* vbase = vt + (size_t)b * 512 * EXTA + s0 + lhi * 8;
  float val[2][4];  // [ni][j]
#pragma unroll
  for (int ni = 0; ni < 2; ++ni) {
    int n = w * 32 + ni * 16 + l15;
    f32x4 acc = {};
    const ushort* vp = vbase + (size_t)n * EXTA;
#pragma unroll
    for (int ks = 0; ks < 9; ++ks) {
      bf16x8 vf = *(const bf16x8*)(vp + ks * 32);
      acc = __builtin_amdgcn_mfma_f32_16x16x32_bf16(pf[ks], vf, acc, 0, 0, 0);
    }
#pragma unroll
    for (int j = 0; j < 4; ++j) {
      int r = lhi * 4 + j;
      val[ni][j] = acc[j] * inv[j] + bf2f(xpe_bf[(size_t)(base0 + r) * 512 + n]);
    }
  }

  // LN1 stats
  float S[4], Q[4];
#pragma unroll
  for (int j = 0; j < 4; ++j) {
    S[j] = 0.f; Q[j] = 0.f;
#pragma unroll
    for (int ni = 0; ni < 2; ++ni) { S[j] += val[ni][j]; Q[j] += val[ni][j] * val[ni][j]; }
  }
#pragma unroll
  for (int off = 1; off <= 8; off <<= 1) {
#pragma unroll
    for (int j = 0; j < 4; ++j) {
      S[j] += __shfl_xor(S[j], off);
      Q[j] += __shfl_xor(Q[j], off);
    }
  }
  if (l15 == 0) {
#pragma unroll
    for (int j = 0; j < 4; ++j) { sm.a.redS[w][lhi * 4 + j] = S[j]; sm.a.redQ[w][lhi * 4 + j] = Q[j]; }
  }
  __syncthreads();
  if (tid < 16) {
    float sS = 0.f, sQ = 0.f;
#pragma unroll
    for (int ww = 0; ww < 16; ++ww) { sS += sm.a.redS[ww][tid]; sQ += sm.a.redQ[ww][tid]; }
    float mu = sS * (1.0f / 512.0f);
    float var = sQ * (1.0f / 512.0f) - mu * mu;
    sm.a.mu[tid] = mu;
    sm.a.rs[tid] = rsqrtf(var + 1e-5f);
  }
  __syncthreads();

#pragma unroll
  for (int ni = 0; ni < 2; ++ni) {
    int n = w * 32 + ni * 16 + l15;
    float lw = ln1w[n], lb = ln1b[n];
#pragma unroll
    for (int j = 0; j < 4; ++j) {
      int r = lhi * 4 + j;
      float o = (val[ni][j] - sm.a.mu[r]) * sm.a.rs[r] * lw + lb;
      x1bf[(size_t)(base0 + r) * 512 + n] = f2bf(o);
    }
  }
}

// ---------------- LN2: sum 2 split-K partials + bias + bf16 residual, layernorm ----------------
__device__ inline float wave_reduce_sum(float v) {
#pragma unroll
  for (int off = 32; off >= 1; off >>= 1) v += __shfl_xor(v, off);
  return v;
}

__global__ __launch_bounds__(256) void ln2_kernel(const float* __restrict__ parts,
                                                  const float* __restrict__ ab,
                                                  const ushort* __restrict__ rsd_bf,
                                                  const float* __restrict__ w,
                                                  const float* __restrict__ bias,
                                                  float* __restrict__ out) {
  const int row = blockIdx.x;
  const int tid = threadIdx.x;
  __shared__ float red[8];
  const int e0 = tid * 2;
  const size_t base = (size_t)row * E_DIM + e0;
  const size_t PART = (size_t)BS_ROWS * E_DIM;
  float2 v0 = *(const float2*)(parts + base);
  float2 v1 = *(const float2*)(parts + PART + base);
  float2 bb = *(const float2*)(ab + e0);
  ushort2 rv = *(const ushort2*)(rsd_bf + base);
  float x0 = v0.x + v1.x + bb.x + bf2f(rv.x);
  float x1 = v0.y + v1.y + bb.y + bf2f(rv.y);

  float sm = wave_reduce_sum(x0 + x1);
  if ((tid & 63) == 0) red[tid >> 6] = sm;
  __syncthreads();
  float mu = (red[0] + red[1] + red[2] + red[3]) * (1.0f / 512.0f);
  float d0 = x0 - mu, d1 = x1 - mu;
  float vs = wave_reduce_sum(d0 * d0 + d1 * d1);
  if ((tid & 63) == 0) red[4 + (tid >> 6)] = vs;
  __syncthreads();
  float var = (red[4] + red[5] + red[6] + red[7]) * (1.0f / 512.0f);
  float inv = rsqrtf(var + 1e-5f);
  float2 wv = *(const float2*)(w + e0);
  float2 bi = *(const float2*)(bias + e0);
  float o0 = d0 * inv * wv.x + bi.x;
  float o1 = d1 * inv * wv.y + bi.y;
  *(float2*)(out + base) = make_float2(o0, o1);
}

// ---------------- launch ----------------
extern "C" void kernel_launch(void* const* d_in, const int* in_sizes, int n_in,
                              void* d_out, int out_size, void* d_ws, size_t ws_size,
                              hipStream_t stream) {
  const float* x    = (const float*)d_in[0];
  const float* wq   = (const float*)d_in[1];
  const float* bq   = (const float*)d_in[2];
  const float* wk   = (const float*)d_in[3];
  const float* bk   = (const float*)d_in[4];
  const float* wv   = (const float*)d_in[5];
  const float* bv   = (const float*)d_in[6];
  const float* w1   = (const float*)d_in[7];
  const float* b1   = (const float*)d_in[8];
  const float* w2   = (const float*)d_in[9];
  const float* b2   = (const float*)d_in[10];
  const float* ln1w = (const float*)d_in[11];
  const float* ln1b = (const float*)d_in[12];
  const float* ln2w = (const float*)d_in[13];
  const float* ln2b = (const float*)d_in[14];

  char* W = (char*)d_ws;
  ushort* xpebf  = (ushort*)(W);                     // 2MB  @0
  ushort* wqkvT  = (ushort*)(W + (2u  << 20));       // 1.5MB@2
  ushort* w1T    = (ushort*)(W + (4u  << 20));       // 2MB  @4
  ushort* w2T    = (ushort*)(W + (6u  << 20));       // 2MB  @6
  ushort* q_bf   = (ushort*)(W + (8u  << 20));       // 2MB  @8
  ushort* k_bf   = (ushort*)(W + (10u << 20));       // 2.6MB@10
  ushort* v_t    = (ushort*)(W + (13u << 20));       // 2.6MB@13
  ushort* x1bf   = (ushort*)(W + (16u << 20));       // 2MB  @16
  ushort* ff1_bf = (ushort*)(W + (18u << 20));       // 8MB  @18
  float*  ff2    = (float*)(W + (26u << 20));        // 2x4MB@26 (split-K partials)

  // prep: PE + wqkv transposes + pads
  prep_kernel<<<3968, 256, 0, stream>>>(x, wq, wk, wv, bk, bv,
                                        xpebf, wqkvT, k_bf, v_t);

  // QKV fused (768 GEMM blocks, 64x64)
  qkv_kernel<<<768, 256, 0, stream>>>(xpebf, wqkvT, bq, bk, bv, q_bf, k_bf, v_t);

  // attention + LN1 (128 blocks, 16 waves) + w1/w2 transposes (2048 blocks)
  attn_ln1<<<2176, 1024, 0, stream>>>(q_bf, k_bf, v_t, xpebf, ln1w, ln1b,
                                      w1, w2, w1T, w2T, x1bf);

  // FFN1: M=2048, N=2048, K=512, relu, bf16 out (1024 blocks)
  mfma_gemm<1><<<dim3(32, 32), 256, 0, stream>>>(
      x1bf, w1T, b1, ff1_bf, BS_ROWS, H_DIM, 512, 512);

  // FFN2: M=2048, N=512, K=2048 split-K x2 -> fp32 partials (512 blocks)
  mfma_gemm<3><<<dim3(8, 32, 2), 256, 0, stream>>>(
      ff1_bf, w2T, nullptr, ff2, BS_ROWS, E_DIM, 1024, 2048);

  // LN2: (2 partials + b2) + x1bf residual
  ln2_kernel<<<BS_ROWS, 256, 0, stream>>>(ff2, b2, x1bf, ln2w, ln2b, (float*)d_out);
}

// Round 14
// 70.074 us; speedup vs baseline: 1.1118x; 1.0058x over previous
//
#include <hip/hip_runtime.h>
#include <hip/hip_bf16.h>

// B=2, S=1024, E=512, H=2048, P=128, W=257
#define S_LEN 1024
#define E_DIM 512
#define H_DIM 2048
#define EXTA 1296              // 128 front pad + 1024 + 128 back pad + 16 zeros (band tiles)
#define BS_ROWS 2048

typedef __attribute__((ext_vector_type(8))) short bf16x8;
typedef __attribute__((ext_vector_type(4))) float f32x4;

__device__ inline ushort f2bf(float x) {
  union { float f; unsigned u; } c; c.f = x;
  unsigned u = c.u;
  u += 0x7fffu + ((u >> 16) & 1u);   // RNE
  return (ushort)(u >> 16);
}
__device__ inline float bf2f(ushort u) {
  union { unsigned u; float f; } c;
  c.u = ((unsigned)u) << 16;
  return c.f;
}

__device__ inline void gload16(ushort* dst, const ushort* src) {
  __builtin_amdgcn_global_load_lds(
      (const __attribute__((address_space(1))) void*)src,
      (__attribute__((address_space(3))) void*)dst, 16, 0, 0);
}

// ---------------- prep: PE add (pair-mapped, fast trig), wqkv transposes, pad fill ----------------
__global__ __launch_bounds__(256) void prep_kernel(const float* __restrict__ x,
                                                   const float* __restrict__ wq,
                                                   const float* __restrict__ wk,
                                                   const float* __restrict__ wv,
                                                   const float* __restrict__ bk,
                                                   const float* __restrict__ bv,
                                                   ushort* __restrict__ xpe_bf,
                                                   ushort* __restrict__ wqkvT,
                                                   ushort* __restrict__ k_bf,
                                                   ushort* __restrict__ v_t) {
  __shared__ float t[32][33];
  const int blk = blockIdx.x;
  if (blk < 1024) {
    int idx = blk * 256 + threadIdx.x;   // pair index: s in [0,1024), ep in [0,256)
    int ep = idx & 255;
    int s = idx >> 8;
    int e0 = ep * 2;
    const float c = -9.210340371976184f / 512.0f;  // -ln(10000)/E
    float freq = __expf((float)e0 * c);
    float sn, cs;
    __sincosf((float)s * freq, &sn, &cs);
    size_t base = (size_t)s * E_DIM + e0;
    float2 x0 = *(const float2*)(x + base);
    float2 x1 = *(const float2*)(x + base + S_LEN * E_DIM);
    ushort2 o0, o1;
    o0.x = f2bf(x0.x + sn); o0.y = f2bf(x0.y + cs);
    o1.x = f2bf(x1.x + sn); o1.y = f2bf(x1.y + cs);
    *(ushort2*)(xpe_bf + base) = o0;
    *(ushort2*)(xpe_bf + base + S_LEN * E_DIM) = o1;
  } else if (blk < 1792) {
    const int tile = blk - 1024;           // 0..767
    const int sect = tile >> 8, tt = tile & 255;
    const float* W = sect == 0 ? wq : (sect == 1 ? wk : wv);
    ushort* WT = wqkvT + (size_t)sect * 512 * 512;
    const int bx = tt & 15, by = tt >> 4;  // K=512, N=512
    int lx = threadIdx.x & 31, ly = threadIdx.x >> 5;  // 32 x 8
    int n0 = bx * 32, k0 = by * 32;
#pragma unroll
    for (int r = 0; r < 4; ++r)
      t[ly + r * 8][lx] = W[(size_t)(k0 + ly + r * 8) * 512 + n0 + lx];
    __syncthreads();
#pragma unroll
    for (int r = 0; r < 4; ++r)
      WT[(size_t)(n0 + ly + r * 8) * 512 + k0 + lx] = f2bf(t[lx][ly + r * 8]);
  } else {
    int p = (blk - 1792) * 256 + threadIdx.x;  // 2 tensors * 2 batch * 272 * 512
    int t2 = p / (2 * 272 * 512);
    int r2 = p % (2 * 272 * 512);
    int b = r2 / (272 * 512);
    int r3 = r2 % (272 * 512);
    if (t2 == 0) {
      int rr = r3 >> 9, e = r3 & 511;
      int row = rr < 128 ? rr : 1024 + rr;   // front 0..127, back 1152..1279, zeros 1280..1295
      float v = rr < 256 ? bk[e] : 0.f;
      k_bf[((size_t)b * EXTA + row) * 512 + e] = f2bf(v);
    } else {
      int n = r3 / 272, jj = r3 % 272;
      int j = jj < 128 ? jj : 1024 + jj;
      float v = jj < 256 ? bv[n] : 0.f;
      v_t[((size_t)b * 512 + n) * EXTA + j] = f2bf(v);
    }
  }
}

// ---------------- QKV GEMM (64x64 tiles, BK=128 -> 4 K-steps, 768 blocks) ----------------
__global__ __launch_bounds__(256, 4) void qkv_kernel(const ushort* __restrict__ A,
                                                     const ushort* __restrict__ Bt,
                                                     const float* __restrict__ bq,
                                                     const float* __restrict__ bk,
                                                     const float* __restrict__ bv,
                                                     ushort* __restrict__ q_out,
                                                     ushort* __restrict__ k_out,
                                                     ushort* __restrict__ v_out) {
  __shared__ ushort As[64 * 128];
  __shared__ ushort Bs[64 * 128];
  const int blk = blockIdx.x;
  const int tid = threadIdx.x;
  const int lane = tid & 63;
  const int w = tid >> 6;
  const int wr = w >> 1, wc = w & 1;   // 2x2 waves: WM=32, WN=32
  const int l15 = lane & 15, lhi = lane >> 4;
  const int col0 = (blk % 24) * 64, row0 = (blk / 24) * 64;

  f32x4 acc[2][2] = {};

  for (int k0 = 0; k0 < 512; k0 += 128) {
    // stage 64x128 tiles: u = r*16 + ch; source chunk pre-swizzled ch^(r&15); LDS linear
#pragma unroll
    for (int it = 0; it < 4; ++it) {
      int u = it * 256 + tid;
      int r = u >> 4;
      int sc = (u & 15) ^ (r & 15);
      gload16(&As[(size_t)u * 8], &A[(size_t)(row0 + r) * 512 + k0 + sc * 8]);
    }
#pragma unroll
    for (int it = 0; it < 4; ++it) {
      int u = it * 256 + tid;
      int r = u >> 4;
      int sc = (u & 15) ^ (r & 15);
      gload16(&Bs[(size_t)u * 8], &Bt[(size_t)(col0 + r) * 512 + k0 + sc * 8]);
    }
    __syncthreads();
#pragma unroll
    for (int kk = 0; kk < 4; ++kk) {
      bf16x8 af[2], bfr[2];
#pragma unroll
      for (int mi = 0; mi < 2; ++mi) {
        int r = wr * 32 + mi * 16 + l15;
        int ch = (kk * 4 + lhi) ^ (r & 15);
        af[mi] = *(const bf16x8*)&As[r * 128 + ch * 8];
      }
#pragma unroll
      for (int ni = 0; ni < 2; ++ni) {
        int r = wc * 32 + ni * 16 + l15;
        int ch = (kk * 4 + lhi) ^ (r & 15);
        bfr[ni] = *(const bf16x8*)&Bs[r * 128 + ch * 8];
      }
#pragma unroll
      for (int mi = 0; mi < 2; ++mi)
#pragma unroll
        for (int ni = 0; ni < 2; ++ni)
          acc[mi][ni] = __builtin_amdgcn_mfma_f32_16x16x32_bf16(af[mi], bfr[ni], acc[mi][ni], 0, 0, 0);
    }
    __syncthreads();
  }

#pragma unroll
  for (int mi = 0; mi < 2; ++mi) {
    int mbase = row0 + wr * 32 + mi * 16 + lhi * 4;
#pragma unroll
    for (int ni = 0; ni < 2; ++ni) {
      int n = col0 + wc * 32 + ni * 16 + l15;
      int sect = n >> 9, nn = n & 511;
      float b = sect == 0 ? bq[nn] : (sect == 1 ? bk[nn] : bv[nn]);
      int bb = mbase >> 10;
      int s = mbase & 1023;
      if (sect == 0) {
#pragma unroll
        for (int j = 0; j < 4; ++j)
          q_out[(size_t)(mbase + j) * 512 + nn] = f2bf(acc[mi][ni][j] + b);
      } else if (sect == 1) {
#pragma unroll
        for (int j = 0; j < 4; ++j)
          k_out[((size_t)bb * EXTA + 128 + s + j) * 512 + nn] = f2bf(acc[mi][ni][j] + b);
      } else {
        ushort4 pk;
        pk.x = f2bf(acc[mi][ni][0] + b);
        pk.y = f2bf(acc[mi][ni][1] + b);
        pk.z = f2bf(acc[mi][ni][2] + b);
        pk.w = f2bf(acc[mi][ni][3] + b);
        *(ushort4*)&v_out[((size_t)bb * 512 + nn) * EXTA + 128 + s] = pk;
      }
    }
  }
}

// ---------------- generic 64x64 MFMA GEMM, BK=128: OUT 1 = bf16+bias+relu; 3 = fp32 split-K partial ----------------
template <int OUT>
__global__ __launch_bounds__(256, 4) void mfma_gemm(const ushort* __restrict__ A,
                                                    const ushort* __restrict__ Bt,
                                                    const float* __restrict__ bias,
                                                    void* __restrict__ Cout,
                                                    int M, int N, int K, int LDA) {
  __shared__ ushort As[64 * 128];
  __shared__ ushort Bs[64 * 128];
  const int tid = threadIdx.x;
  const int lane = tid & 63;
  const int w = tid >> 6;
  const int wr = w >> 1, wc = w & 1;   // 2x2 waves: WM=32, WN=32
  const int l15 = lane & 15, lhi = lane >> 4;
  const int col0 = blockIdx.x * 64, row0 = blockIdx.y * 64;
  const int koff = blockIdx.z * K;

  f32x4 acc[2][2] = {};

  for (int k0 = 0; k0 < K; k0 += 128) {
#pragma unroll
    for (int it = 0; it < 4; ++it) {
      int u = it * 256 + tid;
      int r = u >> 4;
      int sc = (u & 15) ^ (r & 15);
      gload16(&As[(size_t)u * 8], &A[(size_t)(row0 + r) * LDA + koff + k0 + sc * 8]);
    }
#pragma unroll
    for (int it = 0; it < 4; ++it) {
      int u = it * 256 + tid;
      int r = u >> 4;
      int sc = (u & 15) ^ (r & 15);
      gload16(&Bs[(size_t)u * 8], &Bt[(size_t)(col0 + r) * LDA + koff + k0 + sc * 8]);
    }
    __syncthreads();
#pragma unroll
    for (int kk = 0; kk < 4; ++kk) {
      bf16x8 af[2], bfr[2];
#pragma unroll
      for (int mi = 0; mi < 2; ++mi) {
        int r = wr * 32 + mi * 16 + l15;
        int ch = (kk * 4 + lhi) ^ (r & 15);
        af[mi] = *(const bf16x8*)&As[r * 128 + ch * 8];
      }
#pragma unroll
      for (int ni = 0; ni < 2; ++ni) {
        int r = wc * 32 + ni * 16 + l15;
        int ch = (kk * 4 + lhi) ^ (r & 15);
        bfr[ni] = *(const bf16x8*)&Bs[r * 128 + ch * 8];
      }
#pragma unroll
      for (int mi = 0; mi < 2; ++mi)
#pragma unroll
        for (int ni = 0; ni < 2; ++ni)
          acc[mi][ni] = __builtin_amdgcn_mfma_f32_16x16x32_bf16(af[mi], bfr[ni], acc[mi][ni], 0, 0, 0);
    }
    __syncthreads();
  }

#pragma unroll
  for (int mi = 0; mi < 2; ++mi) {
    int mbase = row0 + wr * 32 + mi * 16 + lhi * 4;
#pragma unroll
    for (int ni = 0; ni < 2; ++ni) {
      int n = col0 + wc * 32 + ni * 16 + l15;
      if constexpr (OUT == 1) {
        float b = bias[n];
        ushort* C = (ushort*)Cout;
#pragma unroll
        for (int j = 0; j < 4; ++j)
          C[(size_t)(mbase + j) * N + n] = f2bf(fmaxf(acc[mi][ni][j] + b, 0.f));
      } else {
        float* C = (float*)Cout + (size_t)blockIdx.z * M * N;
#pragma unroll
        for (int j = 0; j < 4; ++j) C[(size_t)(mbase + j) * N + n] = acc[mi][ni][j];
      }
    }
  }
}

// ---------------- attention + LN1 (16 waves, blocks 0..127) + w1/w2 transposes ----------------
union AttnSm {
  struct {
    float e[16][292];
    ushort p[16][296];
    float inv[16];
    float redS[16][16];
    float redQ[16][16];
    float mu[16], rs[16];
  } a;
  float t[32][33];
};

__global__ __launch_bounds__(1024) void attn_ln1(const ushort* __restrict__ qb,
                                                 const ushort* __restrict__ kb,
                                                 const ushort* __restrict__ vt,
                                                 const ushort* __restrict__ xpe_bf,
                                                 const float* __restrict__ ln1w,
                                                 const float* __restrict__ ln1b,
                                                 const float* __restrict__ w1,
                                                 const float* __restrict__ w2,
                                                 ushort* __restrict__ w1T,
                                                 ushort* __restrict__ w2T,
                                                 ushort* __restrict__ x1bf) {
  __shared__ AttnSm sm;
  const int tid = threadIdx.x;

  if (blockIdx.x >= 128) {  // weight transposes, 1024 threads: 32 lx x 32 ly
    const int tile = blockIdx.x - 128;   // 0..2047
    const float* W; ushort* WT; int K, N, bx, by;
    if (tile < 1024) {
      K = 512; N = 2048; W = w1; WT = w1T;
      bx = tile & 63; by = tile >> 6;
    } else {
      K = 2048; N = 512; W = w2; WT = w2T;
      int tt = tile - 1024; bx = tt & 15; by = tt >> 4;
    }
    int lx = tid & 31, ly = tid >> 5;  // ly 0..31
    int n0 = bx * 32, k0 = by * 32;
    sm.t[ly][lx] = W[(size_t)(k0 + ly) * N + n0 + lx];
    __syncthreads();
    WT[(size_t)(n0 + ly) * K + k0 + lx] = f2bf(sm.t[lx][ly]);
    return;
  }

  const int lane = tid & 63;
  const int w = tid >> 6;          // 0..15
  const int l15 = lane & 15, lhi = lane >> 4;
  const int tile = blockIdx.x;     // 0..127
  const int b = tile >> 6;
  const int s0 = (tile & 63) * 16;
  const int base0 = b * 1024 + s0;

  const ushort* qrow = qb + (size_t)(base0 + l15) * 512 + lhi * 8;
  bf16x8 qf[16];
#pragma unroll
  for (int ks = 0; ks < 16; ++ks) qf[ks] = *(const bf16x8*)(qrow + ks * 32);

  const float scale = 0.044194173824159216f;  // 1/sqrt(512)
  const ushort* kbase = kb + (size_t)b * EXTA * 512 + (size_t)(s0 + l15) * 512 + lhi * 8;

  // energy: wave w -> j-tiles {w, w+16}
  for (int jt = w; jt < 18; jt += 16) {
    f32x4 acc = {};
    const ushort* kp = kbase + (size_t)jt * 16 * 512;
#pragma unroll
    for (int ks = 0; ks < 16; ++ks) {
      bf16x8 kf = *(const bf16x8*)(kp + ks * 32);
      acc = __builtin_amdgcn_mfma_f32_16x16x32_bf16(qf[ks], kf, acc, 0, 0, 0);
    }
    int jc = jt * 16 + l15;
#pragma unroll
    for (int j = 0; j < 4; ++j) {
      int i = lhi * 4 + j;
      bool valid = (jc >= i) && (jc <= i + 256);
      sm.a.e[i][jc] = valid ? acc[j] * scale : -1e30f;
    }
  }
  __syncthreads();

  // softmax: one wave per row, 64 lanes over 288 cols (t=4 valid iff lane<32)
  {
    int r = w;
    float m = -1e30f;
#pragma unroll
    for (int t = 0; t < 5; ++t) {
      int col = lane + 64 * t;
      float e = (t < 4 || lane < 32) ? sm.a.e[r][col] : -1e30f;
      m = fmaxf(m, e);
    }
#pragma unroll
    for (int off = 1; off <= 32; off <<= 1) m = fmaxf(m, __shfl_xor(m, off));
    float s = 0.f;
#pragma unroll
    for (int t = 0; t < 5; ++t) {
      int col = lane + 64 * t;
      if (t < 4 || lane < 32) {
        float p = __expf(sm.a.e[r][col] - m);
        s += p;
        sm.a.p[r][col] = f2bf(p);
      }
    }
#pragma unroll
    for (int off = 1; off <= 32; off <<= 1) s += __shfl_xor(s, off);
    if (lane == 0) sm.a.inv[r] = 1.0f / s;
  }
  __syncthreads();

  // PV: wave w -> n-tiles {2w, 2w+1}; bf16 residual
  bf16x8 pf[9];
#pragma unroll
  for (int ks = 0; ks < 9; ++ks) pf[ks] = *(const bf16x8*)&sm.a.p[l15][ks * 32 + lhi * 8];
  float inv[4];
#pragma unroll
  for (int j = 0; j < 4; ++j) inv[j] = sm.a.inv[lhi * 4 + j];

  const ushort* vbase = vt + (size_t)b * 512 * EXTA + s0 + lhi * 8;
  float val[2][4];  // [ni][j]
#pragma unroll
  for (int ni = 0; ni < 2; ++ni) {
    int n = w * 32 + ni * 16 + l15;
    f32x4 acc = {};
    const ushort* vp = vbase + (size_t)n * EXTA;
#pragma unroll
    for (int ks = 0; ks < 9; ++ks) {
      bf16x8 vf = *(const bf16x8*)(vp + ks * 32);
      acc = __builtin_amdgcn_mfma_f32_16x16x32_bf16(pf[ks], vf, acc, 0, 0, 0);
    }
#pragma unroll
    for (int j = 0; j < 4; ++j) {
      int r = lhi * 4 + j;
      val[ni][j] = acc[j] * inv[j] + bf2f(xpe_bf[(size_t)(base0 + r) * 512 + n]);
    }
  }

  // LN1 stats
  float S[4], Q[4];
#pragma unroll
  for (int j = 0; j < 4; ++j) {
    S[j] = 0.f; Q[j] = 0.f;
#pragma unroll
    for (int ni = 0; ni < 2; ++ni) { S[j] += val[ni][j]; Q[j] += val[ni][j] * val[ni][j]; }
  }
#pragma unroll
  for (int off = 1; off <= 8; off <<= 1) {
#pragma unroll
    for (int j = 0; j < 4; ++j) {
      S[j] += __shfl_xor(S[j], off);
      Q[j] += __shfl_xor(Q[j], off);
    }
  }
  if (l15 == 0) {
#pragma unroll
    for (int j = 0; j < 4; ++j) { sm.a.redS[w][lhi * 4 + j] = S[j]; sm.a.redQ[w][lhi * 4 + j] = Q[j]; }
  }
  __syncthreads();
  if (tid < 16) {
    float sS = 0.f, sQ = 0.f;
#pragma unroll
    for (int ww = 0; ww < 16; ++ww) { sS += sm.a.redS[ww][tid]; sQ += sm.a.redQ[ww][tid]; }
    float mu = sS * (1.0f / 512.0f);
    float var = sQ * (1.0f / 512.0f) - mu * mu;
    sm.a.mu[tid] = mu;
    sm.a.rs[tid] = rsqrtf(var + 1e-5f);
  }
  __syncthreads();

#pragma unroll
  for (int ni = 0; ni < 2; ++ni) {
    int n = w * 32 + ni * 16 + l15;
    float lw = ln1w[n], lb = ln1b[n];
#pragma unroll
    for (int j = 0; j < 4; ++j) {
      int r = lhi * 4 + j;
      float o = (val[ni][j] - sm.a.mu[r]) * sm.a.rs[r] * lw + lb;
      x1bf[(size_t)(base0 + r) * 512 + n] = f2bf(o);
    }
  }
}

// ---------------- LN2: sum 2 split-K partials + bias + bf16 residual, layernorm ----------------
__device__ inline float wave_reduce_sum(float v) {
#pragma unroll
  for (int off = 32; off >= 1; off >>= 1) v += __shfl_xor(v, off);
  return v;
}

__global__ __launch_bounds__(256) void ln2_kernel(const float* __restrict__ parts,
                                                  const float* __restrict__ ab,
                                                  const ushort* __restrict__ rsd_bf,
                                                  const float* __restrict__ w,
                                                  const float* __restrict__ bias,
                                                  float* __restrict__ out) {
  const int row = blockIdx.x;
  const int tid = threadIdx.x;
  __shared__ float red[8];
  const int e0 = tid * 2;
  const size_t base = (size_t)row * E_DIM + e0;
  const size_t PART = (size_t)BS_ROWS * E_DIM;
  float2 v0 = *(const float2*)(parts + base);
  float2 v1 = *(const float2*)(parts + PART + base);
  float2 bb = *(const float2*)(ab + e0);
  ushort2 rv = *(const ushort2*)(rsd_bf + base);
  float x0 = v0.x + v1.x + bb.x + bf2f(rv.x);
  float x1 = v0.y + v1.y + bb.y + bf2f(rv.y);

  float sm = wave_reduce_sum(x0 + x1);
  if ((tid & 63) == 0) red[tid >> 6] = sm;
  __syncthreads();
  float mu = (red[0] + red[1] + red[2] + red[3]) * (1.0f / 512.0f);
  float d0 = x0 - mu, d1 = x1 - mu;
  float vs = wave_reduce_sum(d0 * d0 + d1 * d1);
  if ((tid & 63) == 0) red[4 + (tid >> 6)] = vs;
  __syncthreads();
  float var = (red[4] + red[5] + red[6] + red[7]) * (1.0f / 512.0f);
  float inv = rsqrtf(var + 1e-5f);
  float2 wv = *(const float2*)(w + e0);
  float2 bi = *(const float2*)(bias + e0);
  float o0 = d0 * inv * wv.x + bi.x;
  float o1 = d1 * inv * wv.y + bi.y;
  *(float2*)(out + base) = make_float2(o0, o1);
}

// ---------------- launch ----------------
extern "C" void kernel_launch(void* const* d_in, const int* in_sizes, int n_in,
                              void* d_out, int out_size, void* d_ws, size_t ws_size,
                              hipStream_t stream) {
  const float* x    = (const float*)d_in[0];
  const float* wq   = (const float*)d_in[1];
  const float* bq   = (const float*)d_in[2];
  const float* wk   = (const float*)d_in[3];
  const float* bk   = (const float*)d_in[4];
  const float* wv   = (const float*)d_in[5];
  const float* bv   = (const float*)d_in[6];
  const float* w1   = (const float*)d_in[7];
  const float* b1   = (const float*)d_in[8];
  const float* w2   = (const float*)d_in[9];
  const float* b2   = (const float*)d_in[10];
  const float* ln1w = (const float*)d_in[11];
  const float* ln1b = (const float*)d_in[12];
  const float* ln2w = (const float*)d_in[13];
  const float* ln2b = (const float*)d_in[14];

  char* W = (char*)d_ws;
  ushort* xpebf  = (ushort*)(W);                     // 2MB  @0
  ushort* wqkvT  = (ushort*)(W + (2u  << 20));       // 1.5MB@2
  ushort* w1T    = (ushort*)(W + (4u  << 20));       // 2MB  @4
  ushort* w2T    = (ushort*)(W + (6u  << 20));       // 2MB  @6
  ushort* q_bf   = (ushort*)(W + (8u  << 20));       // 2MB  @8
  ushort* k_bf   = (ushort*)(W + (10u << 20));       // 2.6MB@10
  ushort* v_t    = (ushort*)(W + (13u << 20));       // 2.6MB@13
  ushort* x1bf   = (ushort*)(W + (16u << 20));       // 2MB  @16
  ushort* ff1_bf = (ushort*)(W + (18u << 20));       // 8MB  @18
  float*  ff2    = (float*)(W + (26u << 20));        // 2x4MB@26 (split-K partials)

  // prep: PE + wqkv transposes + pads
  prep_kernel<<<3968, 256, 0, stream>>>(x, wq, wk, wv, bk, bv,
                                        xpebf, wqkvT, k_bf, v_t);

  // QKV fused (768 GEMM blocks, 64x64, BK=128)
  qkv_kernel<<<768, 256, 0, stream>>>(xpebf, wqkvT, bq, bk, bv, q_bf, k_bf, v_t);

  // attention + LN1 (128 blocks, 16 waves) + w1/w2 transposes (2048 blocks)
  attn_ln1<<<2176, 1024, 0, stream>>>(q_bf, k_bf, v_t, xpebf, ln1w, ln1b,
                                      w1, w2, w1T, w2T, x1bf);

  // FFN1: M=2048, N=2048, K=512, relu, bf16 out (1024 blocks, BK=128)
  mfma_gemm<1><<<dim3(32, 32), 256, 0, stream>>>(
      x1bf, w1T, b1, ff1_bf, BS_ROWS, H_DIM, 512, 512);

  // FFN2: M=2048, N=512, K=2048 split-K x2 -> fp32 partials (512 blocks, BK=128)
  mfma_gemm<3><<<dim3(8, 32, 2), 256, 0, stream>>>(
      ff1_bf, w2T, nullptr, ff2, BS_ROWS, E_DIM, 1024, 2048);

  // LN2: (2 partials + b2) + x1bf residual
  ln2_kernel<<<BS_ROWS, 256, 0, stream>>>(ff2, b2, x1bf, ln2w, ln2b, (float*)d_out);
}